// Round 6
// baseline (793.196 us; speedup 1.0000x reference)
//
#include <hip/hip_runtime.h>
#include <math.h>

#define BB 4
#define LL 8192
#define NTOK 32768
#define DM 512
#define NH 8
#define HD 64
#define DFF 2048

typedef __attribute__((ext_vector_type(4))) float f32x4;
typedef __attribute__((ext_vector_type(8))) short s16x8;
typedef __attribute__((ext_vector_type(4))) short s16x4;

static __device__ __forceinline__ float bf2f(short u){
  union { unsigned int i; float f; } c; c.i = ((unsigned int)(unsigned short)u) << 16; return c.f;
}
static __device__ __forceinline__ short f2bf(float x){
  union { float f; unsigned int i; } c; c.f = x;
  unsigned int r = c.i + 0x7fffu + ((c.i >> 16) & 1u);
  return (short)(r >> 16);
}

static __device__ __forceinline__ void gload_lds16(const void* g, void* lds){
  __builtin_amdgcn_global_load_lds(
      (const __attribute__((address_space(1))) unsigned int*)g,
      (__attribute__((address_space(3))) unsigned int*)lds, 16, 0, 0);
}

// ---------------- weight convert + transpose (+ optional W1 column perm) ----
__global__ void wconv_kernel(const float* __restrict__ in, short* __restrict__ out,
                             int K, int N, int mode){
  __shared__ float t[32][33];
  int c0 = blockIdx.x*32, k0 = blockIdx.y*32;
  int tx = threadIdx.x, ty = threadIdx.y;
#pragma unroll
  for (int j=0;j<4;j++)
    t[ty+8*j][tx] = in[(size_t)(k0+ty+8*j)*N + c0+tx];
  __syncthreads();
#pragma unroll
  for (int j=0;j<4;j++){
    int c = c0+ty+8*j;
    int p = (mode==1) ? ((c<DFF)? (c<<1) : (((c-DFF)<<1)|1)) : c;
    out[(size_t)p*K + k0+tx] = f2bf(t[tx][ty+8*j]);
  }
}

// ---------------- RoPE tables ----------------
__global__ void rope_table_kernel(float* __restrict__ cosb, float* __restrict__ sinb){
  int i = blockIdx.x*256 + threadIdx.x;
  int l = i >> 5, d = i & 31;
  float inv = powf(10000.f, -(float)d * (1.f/32.f));
  float ang = (float)l * inv;
  cosb[i] = cosf(ang); sinb[i] = sinf(ang);
}

// ---------------- LayerNorm (f32 in -> bf16 out), one row per wave ---------
__global__ __launch_bounds__(256) void ln_kernel(const float* __restrict__ x,
      const float* __restrict__ w, const float* __restrict__ bvec,
      short* __restrict__ out){
  int row = blockIdx.x*4 + (threadIdx.x>>6);
  int lane = threadIdx.x & 63;
  const float4* xr = (const float4*)(x + (size_t)row*DM);
  float4 a = xr[lane*2], b = xr[lane*2+1];
  float v[8] = {a.x,a.y,a.z,a.w,b.x,b.y,b.z,b.w};
  float s = 0.f;
#pragma unroll
  for (int j=0;j<8;j++) s += v[j];
#pragma unroll
  for (int m=1;m<64;m<<=1) s += __shfl_xor(s, m);
  float mu = s * (1.f/512.f);
  float q = 0.f;
#pragma unroll
  for (int j=0;j<8;j++){ float d = v[j]-mu; q += d*d; }
#pragma unroll
  for (int m=1;m<64;m<<=1) q += __shfl_xor(q, m);
  float inv = rsqrtf(q*(1.f/512.f) + 1e-5f);
  int d0 = lane*8;
  s16x8 o;
#pragma unroll
  for (int j=0;j<8;j++) o[j] = f2bf((v[j]-mu)*inv*w[d0+j] + bvec[d0+j]);
  *(s16x8*)(out + (size_t)row*DM + d0) = o;
}

// ---------------- RoPE apply (in-place on q,k head-major bf16) -------------
__global__ __launch_bounds__(256) void rope_kernel(short* __restrict__ qk,
      const float* __restrict__ cosb, const float* __restrict__ sinb){
  int t = blockIdx.x*256 + threadIdx.x;
  int i = t & 31;
  size_t pos = (size_t)(t >> 5);
  int l = (int)(pos & (LL-1));
  float c = cosb[l*32+i], s = sinb[l*32+i];
  short* base = qk + pos*HD;
  float v1 = bf2f(base[i]), v2 = bf2f(base[i+32]);
  base[i]    = f2bf(v1*c - v2*s);
  base[i+32] = f2bf(v2*c + v1*s);
}

// ---------------- GEMM 256x256 8-phase: C = A[M][K] * Bt[N][K]^T -----------
// EPI 0: +bias, scatter to qkv head-major bf16
// EPI 1: +bias +resid(f32), write f32 (x1 -> d_out)
// EPI 2: +bias(perm), swiglu pair via shfl, write bf16 [M][DFF]
// EPI 3: +bias +resid(d_out), write f32 d_out (final)
template<int EPI>
__global__ __launch_bounds__(512,2) void gemm256_kernel(
    const short* __restrict__ A, const short* __restrict__ Bt,
    const float* __restrict__ bias, const float* __restrict__ resid,
    void* __restrict__ outp, int K, short* __restrict__ qkvout)
{
  __shared__ short As[2][16384];  // [buf][256 rows][64 k], row-swizzled
  __shared__ short Bs[2][16384];
  const int tid = threadIdx.x;
  const int w = tid>>6, lane = tid&63;
  const int wm = w>>2, wn = w&3;
  const int l15 = lane&15, l4 = lane>>4;

  // Two-level locality swizzle (xcd = bid%8 round-robin):
  //   mblk = 4*(bid/(4*NB)) + (bid&3)   -> per-XCD mloc residue fixed
  //   nblk = (bid>>2) % NB              -> per-XCD nblks = fixed parity class
  // Per-XCD steady working set: ~4-8 A panels (streamed) + <=NB/2 B panels
  // (hot across all rounds) <= ~3MB -> staging becomes L2-hits.
  const int bid = blockIdx.x;
  const int NB = gridDim.x >> 7;          // N/256 (M is always 32768)
  const int mblk = ((bid >> 2) / NB) * 4 + (bid & 3);
  const int nblk = (bid >> 2) % NB;
  const size_t m0 = (size_t)mblk << 8;
  const size_t n0 = (size_t)nblk << 8;
  const int nt = K >> 6;

  // stage one 128-row half-unit (16KB) of tile kt into LDS unit base.
  // LDS linear dest (gload writes base+lane*16); global source pre-swizzled
  // by the same (row&7)<<4 XOR the reads use (involution).
  auto stage2 = [&](const short* __restrict__ g, int row0g, int kt, short* unitbase){
#pragma unroll
    for (int i=0;i<2;i++){
      int c = w*128 + i*64 + lane;          // 16B chunk in [0,1024)
      int rin = c>>3, s = c&7;
      int grow = row0g + rin;
      gload_lds16((const char*)g + (((size_t)grow*K + (kt<<6))<<1) + ((s ^ (grow&7))<<4),
                  (char*)unitbase + w*2048 + i*1024);
    }
  };

  f32x4 acc[8][4] = {};
  s16x8 aR[4][2], bR[4][2];

  // prologue: stage tiles 0 and 1, wait tile0 (8 younger outstanding = tile1.A)
  stage2(Bt, (int)n0,       0, &Bs[0][0]);
  stage2(Bt, (int)n0 + 128, 0, &Bs[0][8192]);
  stage2(A,  (int)m0,       0, &As[0][0]);
  stage2(A,  (int)m0 + 128, 0, &As[0][8192]);
  if (nt > 1){
    stage2(Bt, (int)n0,       1, &Bs[1][0]);
    stage2(Bt, (int)n0 + 128, 1, &Bs[1][8192]);
    stage2(A,  (int)m0,       1, &As[1][0]);
    stage2(A,  (int)m0 + 128, 1, &As[1][8192]);
    asm volatile("s_waitcnt vmcnt(8)" ::: "memory");
  } else {
    asm volatile("s_waitcnt vmcnt(0)" ::: "memory");
  }
  __builtin_amdgcn_s_barrier();

  for (int t=0; t<nt; ++t){
    const char* Ab = (const char*)As[t&1];
    const char* Bb = (const char*)Bs[t&1];
    const bool st = (t+2) < nt;

    // ---- P0: read A m0-3 (8) + B n0-1 (4); MFMA m0-3 x n0-1
#pragma unroll
    for (int mf=0;mf<4;mf++)
#pragma unroll
      for (int kh=0;kh<2;kh++){
        int row = wm*128 + mf*16 + l15;
        aR[mf][kh] = *(const s16x8*)(Ab + row*128 + (((kh<<6) + (l4<<4)) ^ ((row&7)<<4)));
      }
#pragma unroll
    for (int nf=0;nf<2;nf++)
#pragma unroll
      for (int kh=0;kh<2;kh++){
        int row = wn*64 + nf*16 + l15;
        bR[nf][kh] = *(const s16x8*)(Bb + row*128 + (((kh<<6) + (l4<<4)) ^ ((row&7)<<4)));
      }
    asm volatile("s_waitcnt lgkmcnt(8)" ::: "memory");
    __builtin_amdgcn_s_barrier();
    asm volatile("s_waitcnt lgkmcnt(0)" ::: "memory");
    __builtin_amdgcn_sched_barrier(0);
    __builtin_amdgcn_s_setprio(1);
#pragma unroll
    for (int mf=0;mf<4;mf++)
#pragma unroll
      for (int nf=0;nf<2;nf++)
#pragma unroll
        for (int kh=0;kh<2;kh++)
          acc[mf][nf] = __builtin_amdgcn_mfma_f32_16x16x32_bf16(aR[mf][kh], bR[nf][kh], acc[mf][nf],0,0,0);
    __builtin_amdgcn_s_setprio(0);
    __builtin_amdgcn_s_barrier();

    // ---- P1: read B n2-3 (4); MFMA m0-3 x n2-3
#pragma unroll
    for (int nf=2;nf<4;nf++)
#pragma unroll
      for (int kh=0;kh<2;kh++){
        int row = wn*64 + nf*16 + l15;
        bR[nf][kh] = *(const s16x8*)(Bb + row*128 + (((kh<<6) + (l4<<4)) ^ ((row&7)<<4)));
      }
    __builtin_amdgcn_s_barrier();
    asm volatile("s_waitcnt lgkmcnt(0)" ::: "memory");
    __builtin_amdgcn_sched_barrier(0);
    __builtin_amdgcn_s_setprio(1);
#pragma unroll
    for (int mf=0;mf<4;mf++)
#pragma unroll
      for (int nf=2;nf<4;nf++)
#pragma unroll
        for (int kh=0;kh<2;kh++)
          acc[mf][nf] = __builtin_amdgcn_mfma_f32_16x16x32_bf16(aR[mf][kh], bR[nf][kh], acc[mf][nf],0,0,0);
    __builtin_amdgcn_s_setprio(0);
    __builtin_amdgcn_s_barrier();

    // ---- P2: read A m4-7 (8); stage t+2.B (region dead after P1); MFMA m4-7 x n0-1
#pragma unroll
    for (int mf=0;mf<4;mf++)
#pragma unroll
      for (int kh=0;kh<2;kh++){
        int row = wm*128 + 64 + mf*16 + l15;
        aR[mf][kh] = *(const s16x8*)(Ab + row*128 + (((kh<<6) + (l4<<4)) ^ ((row&7)<<4)));
      }
    if (st){
      stage2(Bt, (int)n0,       t+2, &Bs[t&1][0]);
      stage2(Bt, (int)n0 + 128, t+2, &Bs[t&1][8192]);
    }
    __builtin_amdgcn_s_barrier();
    asm volatile("s_waitcnt lgkmcnt(0)" ::: "memory");
    __builtin_amdgcn_sched_barrier(0);
    __builtin_amdgcn_s_setprio(1);
#pragma unroll
    for (int mf=0;mf<4;mf++)
#pragma unroll
      for (int nf=0;nf<2;nf++)
#pragma unroll
        for (int kh=0;kh<2;kh++)
          acc[mf+4][nf] = __builtin_amdgcn_mfma_f32_16x16x32_bf16(aR[mf][kh], bR[nf][kh], acc[mf+4][nf],0,0,0);
    __builtin_amdgcn_s_setprio(0);
    __builtin_amdgcn_s_barrier();

    // ---- P3: stage t+2.A (region dead after P2); MFMA m4-7 x n2-3; counted vmcnt
    if (st){
      stage2(A, (int)m0,       t+2, &As[t&1][0]);
      stage2(A, (int)m0 + 128, t+2, &As[t&1][8192]);
    }
    __builtin_amdgcn_s_barrier();
    __builtin_amdgcn_s_setprio(1);
#pragma unroll
    for (int mf=0;mf<4;mf++)
#pragma unroll
      for (int nf=2;nf<4;nf++)
#pragma unroll
        for (int kh=0;kh<2;kh++)
          acc[mf+4][nf] = __builtin_amdgcn_mfma_f32_16x16x32_bf16(aR[mf][kh], bR[nf][kh], acc[mf+4][nf],0,0,0);
    __builtin_amdgcn_s_setprio(0);
    if (st)               { asm volatile("s_waitcnt vmcnt(8)" ::: "memory"); }
    else if (t+1 < nt)    { asm volatile("s_waitcnt vmcnt(0)" ::: "memory"); }
    __builtin_amdgcn_s_barrier();
  }

  // ---- epilogue
#pragma unroll
  for (int i=0;i<8;i++){
#pragma unroll
    for (int j=0;j<4;j++){
#pragma unroll
      for (int r=0;r<4;r++){
        size_t m = m0 + wm*128 + i*16 + l4*4 + r;
        int n = (int)n0 + wn*64 + j*16 + l15;
        float val = acc[i][j][r];
        if (EPI == 0){
          val += bias[n];
          int which = n>>9, rem = n&511, hh = rem>>6, dd = rem&63;
          size_t bb = m>>13, lp = m&(LL-1);
          qkvout[((((size_t)which*BB + bb)*NH + hh)*LL + lp)*HD + dd] = f2bf(val);
        } else if (EPI == 1){
          val += bias[n] + resid[m*DM + n];
          ((float*)outp)[m*DM + n] = val;
        } else if (EPI == 2){
          int orig = (n&1) ? (DFF + (n>>1)) : (n>>1);
          val += bias[orig];
          float other = __shfl_xor(val, 1);
          if (!(n&1)){
            float sg = val / (1.f + __expf(-val));
            ((short*)outp)[m*(size_t)DFF + (n>>1)] = f2bf(sg * other);
          }
        } else {
          val += bias[n] + resid[m*DM + n];
          ((float*)outp)[m*DM + n] = val;
        }
      }
    }
  }
}

// ---------------- windowed flash attention ---------------------------------
__global__ __launch_bounds__(256) void attn_kernel(
    const short* __restrict__ q, const short* __restrict__ kk,
    const short* __restrict__ vv, const unsigned char* __restrict__ pad,
    short* __restrict__ outp)
{
  const int qt = blockIdx.x;
  const int bh = blockIdx.y;
  const int b = bh >> 3, h = bh & 7;
  const int q0 = qt*64;
  const int tid = threadIdx.x, w = tid>>6, lane = tid&63;
  const int l15 = lane&15, l4 = lane>>4;
  __shared__ short Ks[32*64];
  __shared__ short Vt[64*48];
  __shared__ short Ps[4][16*32];
  __shared__ float mk[32];

  const short* qb = q  + (size_t)bh*LL*HD;
  const short* kb = kk + (size_t)bh*LL*HD;
  const short* vb = vv + (size_t)bh*LL*HD;
  const int qw0 = q0 + w*16;

  s16x8 qf[2];
#pragma unroll
  for (int c=0;c<2;c++)
    qf[c] = *(const s16x8*)(qb + (size_t)(qw0 + l15)*HD + c*32 + l4*8);

  float mrun = -1e30f, ssum = 0.f;
  f32x4 oacc[4] = {};

  const int kc_lo = (q0 >= 512) ? (q0 - 512) : 0;
  const int kc_hi = q0 + 64;

  for (int kc = kc_lo; kc < kc_hi; kc += 32){
    __syncthreads();
    {
      int o = w*1024 + lane*16;
      int row = o>>7, pb = o&127;
      int sb = pb ^ ((row&7)<<4);
      gload_lds16((const char*)kb + ((size_t)(kc+row)*HD)*2 + sb, (char*)Ks + w*1024);
    }
    {
      int krow = tid>>3, d0 = (tid&7)*8;
      s16x8 vload = *(const s16x8*)(vb + (size_t)(kc+krow)*HD + d0);
#pragma unroll
      for (int j=0;j<8;j++) Vt[(d0+j)*48 + krow] = vload[j];
    }
    if (tid < 32) mk[tid] = pad[(size_t)b*LL + kc + tid] ? -1e30f : 0.f;
    __syncthreads();

    bool active = (kc <= qw0+15) && (kc+31 >= qw0-512);
    float p[8];
    if (active){
      f32x4 st[2] = {};
#pragma unroll
      for (int tt=0;tt<2;tt++){
        int key = tt*16 + l15;
        const char* kr = (const char*)Ks + key*128;
        s16x8 kf0 = *(const s16x8*)(kr + ((l4*16)      ^ ((key&7)<<4)));
        s16x8 kf1 = *(const s16x8*)(kr + ((64 + l4*16) ^ ((key&7)<<4)));
        st[tt] = __builtin_amdgcn_mfma_f32_16x16x32_bf16(kf0, qf[0], st[tt],0,0,0);
        st[tt] = __builtin_amdgcn_mfma_f32_16x16x32_bf16(kf1, qf[1], st[tt],0,0,0);
      }
      int qg = qw0 + l15;
      float mx = -1e30f;
      float sv[8];
#pragma unroll
      for (int tt=0;tt<2;tt++)
#pragma unroll
        for (int r=0;r<4;r++){
          int key = kc + tt*16 + l4*4 + r;
          float xv = st[tt][r]*0.125f + mk[tt*16 + l4*4 + r];
          bool ok = (key <= qg) && (key >= qg-512);
          xv = ok ? xv : -1e30f;
          sv[tt*4+r] = xv;
          mx = fmaxf(mx, xv);
        }
      mx = fmaxf(mx, __shfl_xor(mx,16));
      mx = fmaxf(mx, __shfl_xor(mx,32));
      float mnew = fmaxf(mrun, mx);
      float scale = __expf(mrun - mnew);
      float psum = 0.f;
#pragma unroll
      for (int u=0;u<8;u++){ p[u] = __expf(sv[u]-mnew); psum += p[u]; }
      psum += __shfl_xor(psum,16);
      psum += __shfl_xor(psum,32);
      ssum = ssum*scale + psum;
      mrun = mnew;
#pragma unroll
      for (int dt=0;dt<4;dt++) oacc[dt] *= scale;
    }
    __syncthreads();
    if (active){
      short* pw = Ps[w];
#pragma unroll
      for (int tt=0;tt<2;tt++)
#pragma unroll
        for (int r=0;r<4;r++){
          int klog = tt*16 + l4*4 + r;
          pw[l15*32 + (klog ^ ((l15&3)<<3))] = f2bf(p[tt*4+r]);
        }
    }
    __syncthreads();
    if (active){
      const short* pw = Ps[w];
      s16x8 pf = *(const s16x8*)(pw + l15*32 + ((l4*8) ^ ((l15&3)<<3)));
#pragma unroll
      for (int dt=0;dt<4;dt++){
        s16x8 vf = *(const s16x8*)(Vt + (dt*16 + l15)*48 + l4*8);
        oacc[dt] = __builtin_amdgcn_mfma_f32_16x16x32_bf16(vf, pf, oacc[dt],0,0,0);
      }
    }
  }

  float inv = 1.f / ssum;
#pragma unroll
  for (int dt=0;dt<4;dt++){
    s16x4 ov;
#pragma unroll
    for (int r=0;r<4;r++) ov[r] = f2bf(oacc[dt][r]*inv);
    size_t tok = (size_t)b*LL + q0 + w*16 + l15;
    *(s16x4*)(outp + tok*DM + h*HD + dt*16 + l4*4) = ov;
  }
}

// ---------------------------------------------------------------------------
extern "C" void kernel_launch(void* const* d_in, const int* in_sizes, int n_in,
                              void* d_out, int out_size, void* d_ws, size_t ws_size,
                              hipStream_t stream) {
  const float* x     = (const float*)d_in[0];
  const unsigned char* mask = (const unsigned char*)d_in[1];
  const float* ln1w  = (const float*)d_in[2];
  const float* ln1b  = (const float*)d_in[3];
  const float* Wqkv  = (const float*)d_in[4];
  const float* bqkv  = (const float*)d_in[5];
  const float* Wproj = (const float*)d_in[6];
  const float* bproj = (const float*)d_in[7];
  const float* ln2w  = (const float*)d_in[8];
  const float* ln2b  = (const float*)d_in[9];
  const float* W1    = (const float*)d_in[10];
  const float* b1    = (const float*)d_in[11];
  const float* W2    = (const float*)d_in[12];
  const float* b2    = (const float*)d_in[13];
  float* out = (float*)d_out;

  char* ws = (char*)d_ws;
  size_t off = 0;
  auto alloc = [&](size_t bytes){ size_t o = off; off += (bytes + 255) & ~(size_t)255; return o; };
  short* wt_qkv = (short*)(ws + alloc((size_t)1536*512*2));
  short* wt_proj= (short*)(ws + alloc((size_t)512*512*2));
  short* wt_w1  = (short*)(ws + alloc((size_t)4096*512*2));
  short* wt_w2  = (short*)(ws + alloc((size_t)512*2048*2));
  float* cosb   = (float*)(ws + alloc((size_t)LL*32*4));
  float* sinb   = (float*)(ws + alloc((size_t)LL*32*4));
  short* hbuf   = (short*)(ws + alloc((size_t)NTOK*DM*2));
  short* qkv    = (short*)(ws + alloc((size_t)3*NTOK*DM*2));
  short* attnb  = (short*)(ws + alloc((size_t)NTOK*DM*2));
  short* mlpb   = qkv;  // reuse qkv(96MB)+attnb(32MB) region = exactly NTOK*DFF*2

  dim3 tb32(32,8);
  wconv_kernel<<<dim3(48,16),  tb32, 0, stream>>>(Wqkv,  wt_qkv, 512, 1536, 0);
  wconv_kernel<<<dim3(16,16),  tb32, 0, stream>>>(Wproj, wt_proj, 512, 512, 0);
  wconv_kernel<<<dim3(128,16), tb32, 0, stream>>>(W1,    wt_w1,  512, 4096, 1);
  wconv_kernel<<<dim3(16,64),  tb32, 0, stream>>>(W2,    wt_w2, 2048, 512, 0);
  rope_table_kernel<<<1024, 256, 0, stream>>>(cosb, sinb);

  ln_kernel<<<NTOK/4, 256, 0, stream>>>(x, ln1w, ln1b, hbuf);
  gemm256_kernel<0><<<768, 512, 0, stream>>>(hbuf, wt_qkv, bqkv, nullptr,
                                             nullptr, 512, qkv);
  rope_kernel<<<65536, 256, 0, stream>>>(qkv, cosb, sinb);
  attn_kernel<<<dim3(128,32), 256, 0, stream>>>(qkv, qkv + (size_t)16777216,
                                                qkv + (size_t)33554432, mask, attnb);
  gemm256_kernel<1><<<256, 512, 0, stream>>>(attnb, wt_proj, bproj, x,
                                             out, 512, nullptr);
  ln_kernel<<<NTOK/4, 256, 0, stream>>>(out, ln2w, ln2b, hbuf);
  gemm256_kernel<2><<<2048, 512, 0, stream>>>(hbuf, wt_w1, b1, nullptr,
                                              mlpb, 512, nullptr);
  gemm256_kernel<3><<<256, 512, 0, stream>>>(mlpb, wt_w2, b2, out,
                                             out, 2048, nullptr);
  (void)in_sizes; (void)n_in; (void)out_size; (void)ws_size;
}

// Round 8
// 777.214 us; speedup vs baseline: 1.0206x; 1.0206x over previous
//
#include <hip/hip_runtime.h>
#include <math.h>

#define BB 4
#define LL 8192
#define NTOK 32768
#define DM 512
#define NH 8
#define HD 64
#define DFF 2048

typedef __attribute__((ext_vector_type(4))) float f32x4;
typedef __attribute__((ext_vector_type(8))) short s16x8;
typedef __attribute__((ext_vector_type(4))) short s16x4;

static __device__ __forceinline__ float bf2f(short u){
  union { unsigned int i; float f; } c; c.i = ((unsigned int)(unsigned short)u) << 16; return c.f;
}
static __device__ __forceinline__ short f2bf(float x){
  union { float f; unsigned int i; } c; c.f = x;
  unsigned int r = c.i + 0x7fffu + ((c.i >> 16) & 1u);
  return (short)(r >> 16);
}

static __device__ __forceinline__ void gload_lds16(const void* g, void* lds){
  __builtin_amdgcn_global_load_lds(
      (const __attribute__((address_space(1))) unsigned int*)g,
      (__attribute__((address_space(3))) unsigned int*)lds, 16, 0, 0);
}

// ---------------- fused prep: 4 weight transposes + rope tables ------------
// segments: [0,768) qkv(48x16); [768,1024) proj(16x16); [1024,3072) w1(128x16);
// [3072,4096) w2(16x64); [4096,5120) rope table (1024 blocks x 256 elems)
__global__ void prep_kernel(const float* __restrict__ Wqkv, const float* __restrict__ Wproj,
                            const float* __restrict__ W1, const float* __restrict__ W2,
                            short* __restrict__ o_qkv, short* __restrict__ o_proj,
                            short* __restrict__ o_w1, short* __restrict__ o_w2,
                            float* __restrict__ cosb, float* __restrict__ sinb){
  int bid = blockIdx.x;
  int tx = threadIdx.x, ty = threadIdx.y;
  if (bid >= 4096){
    int i = (bid-4096)*256 + ty*32 + tx;
    int l = i >> 5, d = i & 31;
    float inv = powf(10000.f, -(float)d * (1.f/32.f));
    float ang = (float)l * inv;
    cosb[i] = cosf(ang); sinb[i] = sinf(ang);
    return;
  }
  const float* in; short* out; int K, N, mode, bx, by;
  if (bid < 768)      { in=Wqkv;  out=o_qkv;  K=512;  N=1536; mode=0; bx=bid%48;        by=bid/48; }
  else if (bid < 1024){ int b=bid-768;  in=Wproj; out=o_proj; K=512;  N=512;  mode=0; bx=b%16;  by=b/16; }
  else if (bid < 3072){ int b=bid-1024; in=W1;    out=o_w1;   K=512;  N=4096; mode=1; bx=b%128; by=b/128; }
  else                { int b=bid-3072; in=W2;    out=o_w2;   K=2048; N=512;  mode=0; bx=b%16;  by=b/16; }
  __shared__ float t[32][33];
  int c0 = bx*32, k0 = by*32;
#pragma unroll
  for (int j=0;j<4;j++)
    t[ty+8*j][tx] = in[(size_t)(k0+ty+8*j)*N + c0+tx];
  __syncthreads();
#pragma unroll
  for (int j=0;j<4;j++){
    int c = c0+ty+8*j;
    int p = (mode==1) ? ((c<DFF)? (c<<1) : (((c-DFF)<<1)|1)) : c;
    out[(size_t)p*K + k0+tx] = f2bf(t[tx][ty+8*j]);
  }
}

// ---------------- LayerNorm (f32 in -> bf16 out), one row per wave ---------
__global__ __launch_bounds__(256) void ln_kernel(const float* __restrict__ x,
      const float* __restrict__ w, const float* __restrict__ bvec,
      short* __restrict__ out){
  int row = blockIdx.x*4 + (threadIdx.x>>6);
  int lane = threadIdx.x & 63;
  const float4* xr = (const float4*)(x + (size_t)row*DM);
  float4 a = xr[lane*2], b = xr[lane*2+1];
  float v[8] = {a.x,a.y,a.z,a.w,b.x,b.y,b.z,b.w};
  float s = 0.f;
#pragma unroll
  for (int j=0;j<8;j++) s += v[j];
#pragma unroll
  for (int m=1;m<64;m<<=1) s += __shfl_xor(s, m);
  float mu = s * (1.f/512.f);
  float q = 0.f;
#pragma unroll
  for (int j=0;j<8;j++){ float d = v[j]-mu; q += d*d; }
#pragma unroll
  for (int m=1;m<64;m<<=1) q += __shfl_xor(q, m);
  float inv = rsqrtf(q*(1.f/512.f) + 1e-5f);
  int d0 = lane*8;
  s16x8 o;
#pragma unroll
  for (int j=0;j<8;j++) o[j] = f2bf((v[j]-mu)*inv*w[d0+j] + bvec[d0+j]);
  *(s16x8*)(out + (size_t)row*DM + d0) = o;
}

// ---------------- GEMM 256x256 8-phase: C = A[M][K] * Bt[N][K]^T -----------
// EPI 0: +bias, fused RoPE (q,k), scatter to qkv head-major bf16
// EPI 1: +bias +resid(f32), write f32 (x1 -> d_out)
// EPI 2: +bias(perm), swiglu pair via shfl, write bf16 [M][DFF]
// EPI 3: +bias +resid(d_out), write f32 d_out (final)
template<int EPI>
__global__ __launch_bounds__(512,2) void gemm256_kernel(
    const short* __restrict__ A, const short* __restrict__ Bt,
    const float* __restrict__ bias, const float* __restrict__ resid,
    void* __restrict__ outp, int K, short* __restrict__ qkvout,
    const float* __restrict__ cosb, const float* __restrict__ sinb)
{
  __shared__ short As[2][16384];  // [buf][256 rows][64 k], row-swizzled
  __shared__ short Bs[2][16384];
  const int tid = threadIdx.x;
  const int w = tid>>6, lane = tid&63;
  const int wm = w>>2, wn = w&3;
  const int l15 = lane&15, l4 = lane>>4;

  // Two-level locality swizzle (xcd = bid%8 round-robin):
  //   mblk = 4*(bid/(4*NB)) + (bid&3)   -> per-XCD mloc residue fixed
  //   nblk = (bid>>2) % NB
  const int bid = blockIdx.x;
  const int NB = gridDim.x >> 7;          // N/256 (M is always 32768)
  const int mblk = ((bid >> 2) / NB) * 4 + (bid & 3);
  const int nblk = (bid >> 2) % NB;
  const size_t m0 = (size_t)mblk << 8;
  const size_t n0 = (size_t)nblk << 8;
  const int nt = K >> 6;

  // stage one 128-row half-unit (16KB) of tile kt into LDS unit base.
  // LDS linear dest (gload writes base+lane*16); global source pre-swizzled
  // by the same (row&7)<<4 XOR the reads use (involution).
  auto stage2 = [&](const short* __restrict__ g, int row0g, int kt, short* unitbase){
#pragma unroll
    for (int i=0;i<2;i++){
      int c = w*128 + i*64 + lane;          // 16B chunk in [0,1024)
      int rin = c>>3, s = c&7;
      int grow = row0g + rin;
      gload_lds16((const char*)g + (((size_t)grow*K + (kt<<6))<<1) + ((s ^ (grow&7))<<4),
                  (char*)unitbase + w*2048 + i*1024);
    }
  };

  f32x4 acc[8][4] = {};
  s16x8 aR[4][2], bR[4][2];

  // prologue: stage tiles 0 and 1, wait tile0 (8 younger outstanding = tile1.A)
  stage2(Bt, (int)n0,       0, &Bs[0][0]);
  stage2(Bt, (int)n0 + 128, 0, &Bs[0][8192]);
  stage2(A,  (int)m0,       0, &As[0][0]);
  stage2(A,  (int)m0 + 128, 0, &As[0][8192]);
  if (nt > 1){
    stage2(Bt, (int)n0,       1, &Bs[1][0]);
    stage2(Bt, (int)n0 + 128, 1, &Bs[1][8192]);
    stage2(A,  (int)m0,       1, &As[1][0]);
    stage2(A,  (int)m0 + 128, 1, &As[1][8192]);
    asm volatile("s_waitcnt vmcnt(8)" ::: "memory");
  } else {
    asm volatile("s_waitcnt vmcnt(0)" ::: "memory");
  }
  __builtin_amdgcn_s_barrier();

  for (int t=0; t<nt; ++t){
    const char* Ab = (const char*)As[t&1];
    const char* Bb = (const char*)Bs[t&1];
    const bool st = (t+2) < nt;

    // ---- P0: read A m0-3 (8) + B n0-1 (4); MFMA m0-3 x n0-1
#pragma unroll
    for (int mf=0;mf<4;mf++)
#pragma unroll
      for (int kh=0;kh<2;kh++){
        int row = wm*128 + mf*16 + l15;
        aR[mf][kh] = *(const s16x8*)(Ab + row*128 + (((kh<<6) + (l4<<4)) ^ ((row&7)<<4)));
      }
#pragma unroll
    for (int nf=0;nf<2;nf++)
#pragma unroll
      for (int kh=0;kh<2;kh++){
        int row = wn*64 + nf*16 + l15;
        bR[nf][kh] = *(const s16x8*)(Bb + row*128 + (((kh<<6) + (l4<<4)) ^ ((row&7)<<4)));
      }
    asm volatile("s_waitcnt lgkmcnt(8)" ::: "memory");
    __builtin_amdgcn_s_barrier();
    asm volatile("s_waitcnt lgkmcnt(0)" ::: "memory");
    __builtin_amdgcn_sched_barrier(0);
    __builtin_amdgcn_s_setprio(1);
#pragma unroll
    for (int mf=0;mf<4;mf++)
#pragma unroll
      for (int nf=0;nf<2;nf++)
#pragma unroll
        for (int kh=0;kh<2;kh++)
          acc[mf][nf] = __builtin_amdgcn_mfma_f32_16x16x32_bf16(aR[mf][kh], bR[nf][kh], acc[mf][nf],0,0,0);
    __builtin_amdgcn_s_setprio(0);
    __builtin_amdgcn_s_barrier();

    // ---- P1: read B n2-3 (4); MFMA m0-3 x n2-3
#pragma unroll
    for (int nf=2;nf<4;nf++)
#pragma unroll
      for (int kh=0;kh<2;kh++){
        int row = wn*64 + nf*16 + l15;
        bR[nf][kh] = *(const s16x8*)(Bb + row*128 + (((kh<<6) + (l4<<4)) ^ ((row&7)<<4)));
      }
    __builtin_amdgcn_s_barrier();
    asm volatile("s_waitcnt lgkmcnt(0)" ::: "memory");
    __builtin_amdgcn_sched_barrier(0);
    __builtin_amdgcn_s_setprio(1);
#pragma unroll
    for (int mf=0;mf<4;mf++)
#pragma unroll
      for (int nf=2;nf<4;nf++)
#pragma unroll
        for (int kh=0;kh<2;kh++)
          acc[mf][nf] = __builtin_amdgcn_mfma_f32_16x16x32_bf16(aR[mf][kh], bR[nf][kh], acc[mf][nf],0,0,0);
    __builtin_amdgcn_s_setprio(0);
    __builtin_amdgcn_s_barrier();

    // ---- P2: read A m4-7 (8); stage t+2.B; MFMA m4-7 x n0-1
#pragma unroll
    for (int mf=0;mf<4;mf++)
#pragma unroll
      for (int kh=0;kh<2;kh++){
        int row = wm*128 + 64 + mf*16 + l15;
        aR[mf][kh] = *(const s16x8*)(Ab + row*128 + (((kh<<6) + (l4<<4)) ^ ((row&7)<<4)));
      }
    if (st){
      stage2(Bt, (int)n0,       t+2, &Bs[t&1][0]);
      stage2(Bt, (int)n0 + 128, t+2, &Bs[t&1][8192]);
    }
    __builtin_amdgcn_s_barrier();
    asm volatile("s_waitcnt lgkmcnt(0)" ::: "memory");
    __builtin_amdgcn_sched_barrier(0);
    __builtin_amdgcn_s_setprio(1);
#pragma unroll
    for (int mf=0;mf<4;mf++)
#pragma unroll
      for (int nf=0;nf<2;nf++)
#pragma unroll
        for (int kh=0;kh<2;kh++)
          acc[mf+4][nf] = __builtin_amdgcn_mfma_f32_16x16x32_bf16(aR[mf][kh], bR[nf][kh], acc[mf+4][nf],0,0,0);
    __builtin_amdgcn_s_setprio(0);
    __builtin_amdgcn_s_barrier();

    // ---- P3: stage t+2.A; MFMA m4-7 x n2-3; counted vmcnt
    if (st){
      stage2(A, (int)m0,       t+2, &As[t&1][0]);
      stage2(A, (int)m0 + 128, t+2, &As[t&1][8192]);
    }
    __builtin_amdgcn_s_barrier();
    __builtin_amdgcn_s_setprio(1);
#pragma unroll
    for (int mf=0;mf<4;mf++)
#pragma unroll
      for (int nf=2;nf<4;nf++)
#pragma unroll
        for (int kh=0;kh<2;kh++)
          acc[mf+4][nf] = __builtin_amdgcn_mfma_f32_16x16x32_bf16(aR[mf][kh], bR[nf][kh], acc[mf+4][nf],0,0,0);
    __builtin_amdgcn_s_setprio(0);
    if (st)               { asm volatile("s_waitcnt vmcnt(8)" ::: "memory"); }
    else if (t+1 < nt)    { asm volatile("s_waitcnt vmcnt(0)" ::: "memory"); }
    __builtin_amdgcn_s_barrier();
  }

  // ---- epilogue
  if (EPI == 0){
    // head-major scatter with fused RoPE. Per (i,r): the 4 j-fragments hold
    // all 64 dims of ONE head: dd = j*16+l15; rope pair (d,d+32) = (j, j+2).
    const int which = (int)(n0 >> 9);                      // 0=q,1=k,2=v (uniform)
    const int hh = (((int)n0 & 511) + wn*64) >> 6;          // head (uniform)
#pragma unroll
    for (int i=0;i<8;i++){
#pragma unroll
      for (int r=0;r<4;r++){
        size_t m = m0 + wm*128 + i*16 + l4*4 + r;
        size_t bb = m >> 13;
        int lp = (int)(m & (LL-1));
        float v[4];
#pragma unroll
        for (int j=0;j<4;j++){
          int n = (int)n0 + wn*64 + j*16 + l15;
          v[j] = acc[i][j][r] + bias[n];
        }
        if (which < 2){
#pragma unroll
          for (int j=0;j<2;j++){
            int d = j*16 + l15;
            float c = cosb[lp*32 + d], s = sinb[lp*32 + d];
            float a0 = v[j], a1 = v[j+2];
            v[j]   = a0*c - a1*s;
            v[j+2] = a1*c + a0*s;
          }
        }
        size_t base = ((((size_t)which*BB + bb)*NH + hh)*LL + lp)*HD;
#pragma unroll
        for (int j=0;j<4;j++)
          qkvout[base + j*16 + l15] = f2bf(v[j]);
      }
    }
  } else {
#pragma unroll
    for (int i=0;i<8;i++){
#pragma unroll
      for (int j=0;j<4;j++){
#pragma unroll
        for (int r=0;r<4;r++){
          size_t m = m0 + wm*128 + i*16 + l4*4 + r;
          int n = (int)n0 + wn*64 + j*16 + l15;
          float val = acc[i][j][r];
          if (EPI == 1){
            val += bias[n] + resid[m*DM + n];
            ((float*)outp)[m*DM + n] = val;
          } else if (EPI == 2){
            int orig = (n&1) ? (DFF + (n>>1)) : (n>>1);
            val += bias[orig];
            float other = __shfl_xor(val, 1);
            if (!(n&1)){
              float sg = val / (1.f + __expf(-val));
              ((short*)outp)[m*(size_t)DFF + (n>>1)] = f2bf(sg * other);
            }
          } else {
            val += bias[n] + resid[m*DM + n];
            ((float*)outp)[m*DM + n] = val;
          }
        }
      }
    }
  }
}

// ---------------- windowed flash attention ---------------------------------
__global__ __launch_bounds__(256) void attn_kernel(
    const short* __restrict__ q, const short* __restrict__ kk,
    const short* __restrict__ vv, const unsigned char* __restrict__ pad,
    short* __restrict__ outp)
{
  const int qt = blockIdx.x;
  const int bh = blockIdx.y;
  const int b = bh >> 3, h = bh & 7;
  const int q0 = qt*64;
  const int tid = threadIdx.x, w = tid>>6, lane = tid&63;
  const int l15 = lane&15, l4 = lane>>4;
  __shared__ short Ks[32*64];
  __shared__ short Vt[64*48];
  __shared__ short Ps[4][16*32];
  __shared__ float mk[32];

  const short* qb = q  + (size_t)bh*LL*HD;
  const short* kb = kk + (size_t)bh*LL*HD;
  const short* vb = vv + (size_t)bh*LL*HD;
  const int qw0 = q0 + w*16;

  s16x8 qf[2];
#pragma unroll
  for (int c=0;c<2;c++)
    qf[c] = *(const s16x8*)(qb + (size_t)(qw0 + l15)*HD + c*32 + l4*8);

  float mrun = -1e30f, ssum = 0.f;
  f32x4 oacc[4] = {};

  const int kc_lo = (q0 >= 512) ? (q0 - 512) : 0;
  const int kc_hi = q0 + 64;

  for (int kc = kc_lo; kc < kc_hi; kc += 32){
    __syncthreads();
    {
      int o = w*1024 + lane*16;
      int row = o>>7, pb = o&127;
      int sb = pb ^ ((row&7)<<4);
      gload_lds16((const char*)kb + ((size_t)(kc+row)*HD)*2 + sb, (char*)Ks + w*1024);
    }
    {
      int krow = tid>>3, d0 = (tid&7)*8;
      s16x8 vload = *(const s16x8*)(vb + (size_t)(kc+krow)*HD + d0);
#pragma unroll
      for (int j=0;j<8;j++) Vt[(d0+j)*48 + krow] = vload[j];
    }
    if (tid < 32) mk[tid] = pad[(size_t)b*LL + kc + tid] ? -1e30f : 0.f;
    __syncthreads();

    bool active = (kc <= qw0+15) && (kc+31 >= qw0-512);
    float p[8];
    if (active){
      f32x4 st[2] = {};
#pragma unroll
      for (int tt=0;tt<2;tt++){
        int key = tt*16 + l15;
        const char* kr = (const char*)Ks + key*128;
        s16x8 kf0 = *(const s16x8*)(kr + ((l4*16)      ^ ((key&7)<<4)));
        s16x8 kf1 = *(const s16x8*)(kr + ((64 + l4*16) ^ ((key&7)<<4)));
        st[tt] = __builtin_amdgcn_mfma_f32_16x16x32_bf16(kf0, qf[0], st[tt],0,0,0);
        st[tt] = __builtin_amdgcn_mfma_f32_16x16x32_bf16(kf1, qf[1], st[tt],0,0,0);
      }
      int qg = qw0 + l15;
      float mx = -1e30f;
      float sv[8];
#pragma unroll
      for (int tt=0;tt<2;tt++)
#pragma unroll
        for (int r=0;r<4;r++){
          int key = kc + tt*16 + l4*4 + r;
          float xv = st[tt][r]*0.125f + mk[tt*16 + l4*4 + r];
          bool ok = (key <= qg) && (key >= qg-512);
          xv = ok ? xv : -1e30f;
          sv[tt*4+r] = xv;
          mx = fmaxf(mx, xv);
        }
      mx = fmaxf(mx, __shfl_xor(mx,16));
      mx = fmaxf(mx, __shfl_xor(mx,32));
      float mnew = fmaxf(mrun, mx);
      float scale = __expf(mrun - mnew);
      float psum = 0.f;
#pragma unroll
      for (int u=0;u<8;u++){ p[u] = __expf(sv[u]-mnew); psum += p[u]; }
      psum += __shfl_xor(psum,16);
      psum += __shfl_xor(psum,32);
      ssum = ssum*scale + psum;
      mrun = mnew;
#pragma unroll
      for (int dt=0;dt<4;dt++) oacc[dt] *= scale;
    }
    __syncthreads();
    if (active){
      short* pw = Ps[w];
#pragma unroll
      for (int tt=0;tt<2;tt++)
#pragma unroll
        for (int r=0;r<4;r++){
          int klog = tt*16 + l4*4 + r;
          pw[l15*32 + (klog ^ ((l15&3)<<3))] = f2bf(p[tt*4+r]);
        }
    }
    __syncthreads();
    if (active){
      const short* pw = Ps[w];
      s16x8 pf = *(const s16x8*)(pw + l15*32 + ((l4*8) ^ ((l15&3)<<3)));
#pragma unroll
      for (int dt=0;dt<4;dt++){
        s16x8 vf = *(const s16x8*)(Vt + (dt*16 + l15)*48 + l4*8);
        oacc[dt] = __builtin_amdgcn_mfma_f32_16x16x32_bf16(vf, pf, oacc[dt],0,0,0);
      }
    }
  }

  float inv = 1.f / ssum;
#pragma unroll
  for (int dt=0;dt<4;dt++){
    s16x4 ov;
#pragma unroll
    for (int r=0;r<4;r++) ov[r] = f2bf(oacc[dt][r]*inv);
    size_t tok = (size_t)b*LL + q0 + w*16 + l15;
    *(s16x4*)(outp + tok*DM + h*HD + dt*16 + l4*4) = ov;
  }
}

// ---------------------------------------------------------------------------
extern "C" void kernel_launch(void* const* d_in, const int* in_sizes, int n_in,
                              void* d_out, int out_size, void* d_ws, size_t ws_size,
                              hipStream_t stream) {
  const float* x     = (const float*)d_in[0];
  const unsigned char* mask = (const unsigned char*)d_in[1];
  const float* ln1w  = (const float*)d_in[2];
  const float* ln1b  = (const float*)d_in[3];
  const float* Wqkv  = (const float*)d_in[4];
  const float* bqkv  = (const float*)d_in[5];
  const float* Wproj = (const float*)d_in[6];
  const float* bproj = (const float*)d_in[7];
  const float* ln2w  = (const float*)d_in[8];
  const float* ln2b  = (const float*)d_in[9];
  const float* W1    = (const float*)d_in[10];
  const float* b1    = (const float*)d_in[11];
  const float* W2    = (const float*)d_in[12];
  const float* b2    = (const float*)d_in[13];
  float* out = (float*)d_out;

  char* ws = (char*)d_ws;
  size_t off = 0;
  auto alloc = [&](size_t bytes){ size_t o = off; off += (bytes + 255) & ~(size_t)255; return o; };
  short* wt_qkv = (short*)(ws + alloc((size_t)1536*512*2));
  short* wt_proj= (short*)(ws + alloc((size_t)512*512*2));
  short* wt_w1  = (short*)(ws + alloc((size_t)4096*512*2));
  short* wt_w2  = (short*)(ws + alloc((size_t)512*2048*2));
  float* cosb   = (float*)(ws + alloc((size_t)LL*32*4));
  float* sinb   = (float*)(ws + alloc((size_t)LL*32*4));
  short* hbuf   = (short*)(ws + alloc((size_t)NTOK*DM*2));
  short* qkv    = (short*)(ws + alloc((size_t)3*NTOK*DM*2));
  short* attnb  = (short*)(ws + alloc((size_t)NTOK*DM*2));
  short* mlpb   = qkv;  // reuse qkv(96MB)+attnb(32MB) region = exactly NTOK*DFF*2

  prep_kernel<<<5120, dim3(32,8), 0, stream>>>(Wqkv, Wproj, W1, W2,
                                               wt_qkv, wt_proj, wt_w1, wt_w2,
                                               cosb, sinb);

  ln_kernel<<<NTOK/4, 256, 0, stream>>>(x, ln1w, ln1b, hbuf);
  gemm256_kernel<0><<<768, 512, 0, stream>>>(hbuf, wt_qkv, bqkv, nullptr,
                                             nullptr, 512, qkv, cosb, sinb);
  attn_kernel<<<dim3(128,32), 256, 0, stream>>>(qkv, qkv + (size_t)16777216,
                                                qkv + (size_t)33554432, mask, attnb);
  gemm256_kernel<1><<<256, 512, 0, stream>>>(attnb, wt_proj, bproj, x,
                                             out, 512, nullptr, nullptr, nullptr);
  ln_kernel<<<NTOK/4, 256, 0, stream>>>(out, ln2w, ln2b, hbuf);
  gemm256_kernel<2><<<2048, 512, 0, stream>>>(hbuf, wt_w1, b1, nullptr,
                                              mlpb, 512, nullptr, nullptr, nullptr);
  gemm256_kernel<3><<<256, 512, 0, stream>>>(mlpb, wt_w2, b2, out,
                                             out, 2048, nullptr, nullptr, nullptr);
  (void)in_sizes; (void)n_in; (void)out_size; (void)ws_size;
}